// Round 4
// baseline (90.572 us; speedup 1.0000x reference)
//
#include <hip/hip_runtime.h>
#include <math.h>

// Problem constants
#define NBATCH 4
#define NCLS   19
#define HWDIM  512
#define HW     (512 * 512)      // 262144
#define PH     171              // pooled H=W
#define PP2    (171 * 171)      // 29241
#define NHW    169              // PH - radius + 1
#define MM     (169 * 169)      // 28561
#define ZSPLIT 2                // stage2 row-split

typedef float f4 __attribute__((ext_vector_type(4)));

// ---------------------------------------------------------------------------
// Stage 1: fused softmax + one-hot + 3x3/stride-3 avg-pool (pad=1, /9 always).
// One block per (n, pooled-row ph); 384 threads = 3 input rows x 128 float4
// column groups. All class-plane loads are float4 (16B/lane). Softmax exp
// values live in v[19] (compile-time indexed). 19 unrolled class rounds:
// write per-row prob/onehot to LDS, 171 pool threads reduce 3x3 and store.
// ---------------------------------------------------------------------------
__global__ __launch_bounds__(384) void stage1_pool(
    const float* __restrict__ cls, const int* __restrict__ label,
    float* __restrict__ P, float* __restrict__ L) {
  int n   = blockIdx.x / PH;
  int ph  = blockIdx.x - n * PH;
  int t   = threadIdx.x;
  int row = t >> 7;              // 0..2
  int c4  = (t & 127) << 2;      // column base 0,4,...,508

  int r = 3 * ph - 1 + row;
  bool rowok = (r >= 0) && (r < HWDIM);

  f4 v[NCLS];
  f4 mx, se, inv;
  int lb0 = -1, lb1 = -1, lb2 = -1, lb3 = -1;
  f4 vmask = {0.f, 0.f, 0.f, 0.f};

  if (rowok) {
    const int4 lq = *(const int4*)(label + ((size_t)n * HWDIM + r) * HWDIM + c4);
    lb0 = lq.x; lb1 = lq.y; lb2 = lq.z; lb3 = lq.w;
    vmask.x = (lb0 >= 0 && lb0 < NCLS) ? 1.f : 0.f;
    vmask.y = (lb1 >= 0 && lb1 < NCLS) ? 1.f : 0.f;
    vmask.z = (lb2 >= 0 && lb2 < NCLS) ? 1.f : 0.f;
    vmask.w = (lb3 >= 0 && lb3 < NCLS) ? 1.f : 0.f;

    const float* base = cls + (size_t)n * NCLS * HW + (size_t)r * HWDIM + c4;
#pragma unroll
    for (int c = 0; c < NCLS; ++c)
      v[c] = *(const f4*)(base + (size_t)c * HW);

    mx = v[0];
#pragma unroll
    for (int c = 1; c < NCLS; ++c) {
#pragma unroll
      for (int j = 0; j < 4; ++j) mx[j] = fmaxf(mx[j], v[c][j]);
    }
    se = (f4){0.f, 0.f, 0.f, 0.f};
#pragma unroll
    for (int c = 0; c < NCLS; ++c) {
#pragma unroll
      for (int j = 0; j < 4; ++j) {
        v[c][j] = expf(v[c][j] - mx[j]);
        se[j] += v[c][j];
      }
    }
#pragma unroll
    for (int j = 0; j < 4; ++j) inv[j] = vmask[j] / se[j];
  } else {
#pragma unroll
    for (int c = 0; c < NCLS; ++c) v[c] = (f4){0.f, 0.f, 0.f, 0.f};
    inv = (f4){0.f, 0.f, 0.f, 0.f};
  }

  __shared__ float xbP[3][512];
  __shared__ float xbL[3][512];
  const float inv9 = 1.f / 9.f;
  int pw = t;  // pool thread's pooled column

#pragma unroll
  for (int c = 0; c < NCLS; ++c) {
    // per-row write (float4, aligned)
    f4 pv, lv;
#pragma unroll
    for (int j = 0; j < 4; ++j) pv[j] = v[c][j] * inv[j];
    lv.x = (lb0 == c) ? vmask.x : 0.f;
    lv.y = (lb1 == c) ? vmask.y : 0.f;
    lv.z = (lb2 == c) ? vmask.z : 0.f;
    lv.w = (lb3 == c) ? vmask.w : 0.f;
    *(f4*)&xbP[row][c4] = pv;
    *(f4*)&xbL[row][c4] = lv;
    __syncthreads();
    if (pw < PH) {
      int x0 = 3 * pw - 1;
      float sP = 0.f, sL = 0.f;
#pragma unroll
      for (int i = 0; i < 3; ++i) {
        float a = (pw > 0) ? xbP[i][x0] : 0.f;
        float b = (pw > 0) ? xbL[i][x0] : 0.f;
        sP += a + xbP[i][x0 + 1] + xbP[i][x0 + 2];
        sL += b + xbL[i][x0 + 1] + xbL[i][x0 + 2];
      }
      size_t o = ((size_t)(n * NCLS + c)) * PP2 + (size_t)ph * PH + pw;
      P[o] = sP * inv9;
      L[o] = sL * inv9;
    }
    __syncthreads();
  }
}

// ---------------------------------------------------------------------------
// Stage 2: per (n,c) raw-moment accumulation over M=169^2 window positions.
// Sliding window in y with 1-row-deep software prefetch: row y+3 loads issue
// before the FMA burst for window rows y..y+2. Grid (76, 3 parts, ZSPLIT).
// Moment layout per (z,nc) record, stride 192 floats:
//   [0..8] sum la | [9..17] sum pr | [18..62] la*la ut45 | [63..107] pr*pr ut45
//   [108..188] pr[d]*la[e] (81) | [190..191] (double) logdet (z=0 only)
// ---------------------------------------------------------------------------
template <int PART>
__device__ __forceinline__ void mom_body(
    int nc, int z, const float* __restrict__ P, const float* __restrict__ L,
    float* __restrict__ covp, float* red) {
  constexpr int NA  = (PART == 0) ? 63 : (PART == 1 ? 45 : 81);
  constexpr int OFF = (PART == 0) ? 0  : (PART == 1 ? 63 : 108);
  const float* Pp = P + (size_t)nc * PP2;
  const float* Lp = L + (size_t)nc * PP2;

  float acc[NA];
#pragma unroll
  for (int k = 0; k < NA; ++k) acc[k] = 0.f;

  int task = threadIdx.x;  // 507 tasks: (ysub, xx)
  if (task < 3 * NHW) {
    int ysub = task / NHW;
    int xx   = task - ysub * NHW;
    int base = z * 85;
    int rt   = (z == 0) ? 85 : (NHW - 85);
    int y0 = base + (rt * ysub) / 3;
    int y1 = base + (rt * (ysub + 1)) / 3;

    float wp[9], wl[9], pfp[3], pfl[3];
    // prime rows y0, y0+1 -> slots 0..5; prefetch row y0+2
#pragma unroll
    for (int dy = 0; dy < 2; ++dy) {
#pragma unroll
      for (int dx = 0; dx < 3; ++dx) {
        wp[dy * 3 + dx] = Pp[(y0 + dy) * PH + xx + dx];
        if (PART != 1) wl[dy * 3 + dx] = Lp[(y0 + dy) * PH + xx + dx];
      }
    }
#pragma unroll
    for (int dx = 0; dx < 3; ++dx) {
      pfp[dx] = Pp[(y0 + 2) * PH + xx + dx];
      if (PART != 1) pfl[dx] = Lp[(y0 + 2) * PH + xx + dx];
    }

    for (int y = y0; y < y1; ++y) {
      // commit prefetch into window slots 6..8
#pragma unroll
      for (int dx = 0; dx < 3; ++dx) {
        wp[6 + dx] = pfp[dx];
        if (PART != 1) wl[6 + dx] = pfl[dx];
      }
      // issue next prefetch (row y+3, clamped; unused garbage on last iter)
      int yn = y + 3; if (yn > PH - 1) yn = PH - 1;
#pragma unroll
      for (int dx = 0; dx < 3; ++dx) {
        pfp[dx] = Pp[yn * PH + xx + dx];
        if (PART != 1) pfl[dx] = Lp[yn * PH + xx + dx];
      }
      // FMA burst on current window
      if (PART == 0) {
#pragma unroll
        for (int d = 0; d < 9; ++d) {
          acc[d]     += wl[d];
          acc[9 + d] += wp[d];
        }
        int k = 18;
#pragma unroll
        for (int d = 0; d < 9; ++d)
#pragma unroll
          for (int e = d; e < 9; ++e) { acc[k] += wl[d] * wl[e]; ++k; }
      } else if (PART == 1) {
        int k = 0;
#pragma unroll
        for (int d = 0; d < 9; ++d)
#pragma unroll
          for (int e = d; e < 9; ++e) { acc[k] += wp[d] * wp[e]; ++k; }
      } else {
#pragma unroll
        for (int d = 0; d < 9; ++d)
#pragma unroll
          for (int e = 0; e < 9; ++e) acc[d * 9 + e] += wp[d] * wl[e];
      }
      // shift window up one row (static indices)
#pragma unroll
      for (int s = 0; s < 6; ++s) {
        wp[s] = wp[s + 3];
        if (PART != 1) wl[s] = wl[s + 3];
      }
    }
  }

  int lane = threadIdx.x & 63;
  int wid  = threadIdx.x >> 6;  // 8 waves
#pragma unroll
  for (int k = 0; k < NA; ++k) {
    float v = acc[k];
#pragma unroll
    for (int o = 32; o > 0; o >>= 1) v += __shfl_down(v, o, 64);
    if (lane == 0) red[wid * NA + k] = v;
  }
  __syncthreads();
  if (threadIdx.x < NA) {
    float s = 0.f;
#pragma unroll
    for (int w = 0; w < 8; ++w) s += red[w * NA + threadIdx.x];
    covp[((size_t)z * NBATCH * NCLS + nc) * 192 + OFF + threadIdx.x] = s;
  }
}

__global__ __launch_bounds__(512) void stage2_mom(
    const float* __restrict__ P, const float* __restrict__ L,
    float* __restrict__ covp) {
  __shared__ float red[8 * 81];
  int nc = blockIdx.x;
  int z  = blockIdx.z;
  if (blockIdx.y == 0)      mom_body<0>(nc, z, P, L, covp, red);
  else if (blockIdx.y == 1) mom_body<1>(nc, z, P, L, covp, red);
  else                      mom_body<2>(nc, z, P, L, covp, red);
}

// ---------------------------------------------------------------------------
// Stage 3: one 64-thread block per (n,c). Sums the ZSPLIT partials, builds
// covariances in fp64 in LDS, Cholesky(la_cov+1e-5 I), triangular solve,
// Schur complement + 1e-6 I, Cholesky logdet. Result -> covp[nc*192+190..191].
// ---------------------------------------------------------------------------
__global__ __launch_bounds__(64) void stage3_rmi(float* __restrict__ covp) {
  int nc  = blockIdx.x;
  int tid = threadIdx.x;
  const float* s0 = covp + (size_t)nc * 192;
  const float* s1 = covp + ((size_t)NBATCH * NCLS + nc) * 192;
  __shared__ double lc[81], pc[81], plc[81], mla[9], mpr[9];
  const double Minv = 1.0 / (double)MM;
#define LDM(k) ((double)s0[k] + (double)s1[k])

  if (tid < 9)       mla[tid]     = LDM(tid) * Minv;
  else if (tid < 18) mpr[tid - 9] = LDM(tid) * Minv;
  __syncthreads();

  for (int e = tid; e < 81; e += 64) {
    int r = e / 9, c = e - 9 * (e / 9);
    int lo = r < c ? r : c, hi = r < c ? c : r;
    int k = lo * 9 - lo * (lo - 1) / 2 + (hi - lo);
    double a = LDM(18 + k) * Minv - mla[r] * mla[c];
    if (r == c) a += 1e-5;
    lc[e] = a;
    pc[e] = LDM(63 + k) * Minv - mpr[r] * mpr[c];
    plc[e] = LDM(108 + e) * Minv - mpr[r] * mla[c];
  }
  __syncthreads();

  // Cholesky of lc (lower), column-by-column
  for (int j = 0; j < 9; ++j) {
    if (tid == 0) lc[j * 9 + j] = sqrt(lc[j * 9 + j]);
    __syncthreads();
    if (tid > j && tid < 9) lc[tid * 9 + j] /= lc[j * 9 + j];
    __syncthreads();
    if (tid > j && tid < 9) {
      double lij = lc[tid * 9 + j];
      for (int k = j + 1; k <= tid; ++k) lc[tid * 9 + k] -= lij * lc[k * 9 + j];
    }
    __syncthreads();
  }

  // Solve W * L1^T = plc (row d per lane), in place
  if (tid < 9) {
    int d = tid;
    for (int j = 0; j < 9; ++j) {
      double t = plc[d * 9 + j];
      for (int k = 0; k < j; ++k) t -= plc[d * 9 + k] * lc[j * 9 + k];
      plc[d * 9 + j] = t / lc[j * 9 + j];
    }
  }
  __syncthreads();

  // A = pc - W W^T + 1e-6 I (in place in pc)
  for (int e = tid; e < 81; e += 64) {
    int r = e / 9, c = e - 9 * (e / 9);
    double a = pc[e];
    for (int f = 0; f < 9; ++f) a -= plc[r * 9 + f] * plc[c * 9 + f];
    if (r == c) a += 1e-6;
    pc[e] = a;
  }
  __syncthreads();

  // Cholesky of pc
  for (int j = 0; j < 9; ++j) {
    if (tid == 0) pc[j * 9 + j] = sqrt(pc[j * 9 + j]);
    __syncthreads();
    if (tid > j && tid < 9) pc[tid * 9 + j] /= pc[j * 9 + j];
    __syncthreads();
    if (tid > j && tid < 9) {
      double lij = pc[tid * 9 + j];
      for (int k = j + 1; k <= tid; ++k) pc[tid * 9 + k] -= lij * pc[k * 9 + j];
    }
    __syncthreads();
  }

  if (tid == 0) {
    double sl = 0.0;
    for (int j = 0; j < 9; ++j) sl += log(pc[j * 9 + j] + 1e-8);
    *(double*)(covp + (size_t)nc * 192 + 190) = sl;  // rmi_{n,c}
  }
#undef LDM
}

// ---------------------------------------------------------------------------
// Stage 4: reduce 76 fp64 partials -> out[0] = sum / (N * NUM_CLASSES)
// ---------------------------------------------------------------------------
__global__ __launch_bounds__(64) void stage4_reduce(
    const float* __restrict__ covp, float* __restrict__ out) {
  int tid = threadIdx.x;
  double v = 0.0;
  if (tid < NBATCH * NCLS)
    v = *(const double*)(covp + (size_t)tid * 192 + 190);
  if (tid + 64 < NBATCH * NCLS)
    v += *(const double*)(covp + (size_t)(tid + 64) * 192 + 190);
#pragma unroll
  for (int o = 32; o > 0; o >>= 1) v += __shfl_down(v, o, 64);
  if (tid == 0) out[0] = (float)(v / (double)(NBATCH * NCLS));
}

// ---------------------------------------------------------------------------
extern "C" void kernel_launch(void* const* d_in, const int* in_sizes, int n_in,
                              void* d_out, int out_size, void* d_ws, size_t ws_size,
                              hipStream_t stream) {
  const float* cls  = (const float*)d_in[0];
  const int* label  = (const int*)d_in[1];
  float* out = (float*)d_out;

  float* P    = (float*)d_ws;                              // 76*29241 f32
  float* L    = P + (size_t)NBATCH * NCLS * PP2;           // 76*29241 f32
  float* covp = L + (size_t)NBATCH * NCLS * PP2;           // 2*76*192 f32

  stage1_pool<<<NBATCH * PH, 384, 0, stream>>>(cls, label, P, L);
  dim3 g2(NBATCH * NCLS, 3, ZSPLIT);
  stage2_mom<<<g2, 512, 0, stream>>>(P, L, covp);
  stage3_rmi<<<NBATCH * NCLS, 64, 0, stream>>>(covp);
  stage4_reduce<<<1, 64, 0, stream>>>(covp, out);
}